// Round 15
// baseline (45.254 us; speedup 1.0000x reference)
//
#include <hip/hip_runtime.h>

typedef _Float16 f16x8 __attribute__((ext_vector_type(8)));
typedef float f32x4 __attribute__((ext_vector_type(4)));

__device__ __forceinline__ unsigned short f2h(float f) {
  union { _Float16 h; unsigned short u; } v;
  v.h = (_Float16)f;
  return v.u;
}
__device__ __forceinline__ f16x8 splat8(float w) {
  _Float16 h = (_Float16)w;
  f16x8 v = {h, h, h, h, h, h, h, h};
  return v;
}

// ---------------- kernel 0: merged prep ----------------
// bid < 1024 : x NCHW f32 -> NHWC f16 xt[b][h][w][c]
// bid >= 1024: weight f32 [O][C][9] -> FRAG-MAJOR f16 wfrag[g][kt][lane][8]
__global__ __launch_bounds__(256) void prep_wx(
    const float* __restrict__ x, const float* __restrict__ w,
    unsigned short* __restrict__ xt, uint4* __restrict__ wfrag) {
  const int bid = blockIdx.x;
  const int t = threadIdx.x;
  if (bid >= 1024) {
    const int idx = (bid - 1024) * 256 + t;  // 0..73727
    const int l = idx & 63;
    const int kt = (idx >> 6) % 72;
    const int g = idx / (72 * 64);  // 0..15
    const int o = g * 16 + (l & 15);
    const int kbase = kt * 32 + ((l >> 4) * 8);
    unsigned short h[8];
#pragma unroll
    for (int e = 0; e < 8; ++e) {
      const int klin = kbase + e;
      const int kk = klin >> 8;
      const int c = klin & 255;
      h[e] = f2h(w[((size_t)o * 256 + c) * 9 + kk]);
    }
    uint4 p;
    p.x = (unsigned)h[0] | ((unsigned)h[1] << 16);
    p.y = (unsigned)h[2] | ((unsigned)h[3] << 16);
    p.z = (unsigned)h[4] | ((unsigned)h[5] << 16);
    p.w = (unsigned)h[6] | ((unsigned)h[7] << 16);
    wfrag[idx] = p;
    return;
  }
  const int b = bid >> 8;
  const int h = (bid >> 2) & 63;
  const int cq = bid & 3;
  const int wave = t >> 6, lane = t & 63;
  __shared__ float lds[64][65];
  const int wpos = t >> 2, sub = t & 3;
  const int cl0 = wave * 4 + (lane >> 4);
  const int w0 = (lane & 15) * 4;
#pragma unroll
  for (int iter = 0; iter < 4; ++iter) {
    const int cl = iter * 16 + cl0;
    const int c = cq * 64 + cl;
    float4 v = *(const float4*)(x + (((size_t)b * 256 + c) * 64 + h) * 64 + w0);
    lds[cl][w0] = v.x; lds[cl][w0 + 1] = v.y;
    lds[cl][w0 + 2] = v.z; lds[cl][w0 + 3] = v.w;
  }
  __syncthreads();
  unsigned short hb[16];
#pragma unroll
  for (int j = 0; j < 16; ++j) hb[j] = f2h(lds[sub * 16 + j][wpos]);
  uint4 p0, p1;
  p0.x = (unsigned)hb[0] | ((unsigned)hb[1] << 16);
  p0.y = (unsigned)hb[2] | ((unsigned)hb[3] << 16);
  p0.z = (unsigned)hb[4] | ((unsigned)hb[5] << 16);
  p0.w = (unsigned)hb[6] | ((unsigned)hb[7] << 16);
  p1.x = (unsigned)hb[8] | ((unsigned)hb[9] << 16);
  p1.y = (unsigned)hb[10] | ((unsigned)hb[11] << 16);
  p1.z = (unsigned)hb[12] | ((unsigned)hb[13] << 16);
  p1.w = (unsigned)hb[14] | ((unsigned)hb[15] << 16);
  unsigned short* dst = xt + (((size_t)b * 64 + h) * 64 + wpos) * 256 + cq * 64 + sub * 16;
  *(uint4*)dst = p0;
  *(uint4*)(dst + 8) = p1;
}

// ---------------- fused: A-in-VGPR, lgkm-only barriers, superphase-2 ---------
// block = (b, nt=h). Out tile [256 o][64 hw]. 36 K64 tiles, 18 barriers
// (2 tiles per superphase). 512 thr = 8 waves; wave owns 32 rows, fm=2 x fn=4
// x 2 ksub = 16 MFMA/tile. Bs = 4-slot ring (slot = tile&3). No VMEM in any
// barrier; A/taps certified per-wave by compiler-counted vmcnt (>=1 superphase
// slack each).
__device__ __forceinline__ void combine8(uint4 q0, uint4 q1, uint4 q2, uint4 q3,
                                         float4 wt, _Float16* dst) {
  f16x8 t0, t1, t2, t3;
  __builtin_memcpy(&t0, &q0, 16);
  __builtin_memcpy(&t1, &q1, 16);
  __builtin_memcpy(&t2, &q2, 16);
  __builtin_memcpy(&t3, &q3, 16);
  f16x8 r = t0 * splat8(wt.x);
  r += t1 * splat8(wt.y);
  r += t2 * splat8(wt.z);
  r += t3 * splat8(wt.w);
  __builtin_memcpy(dst, &r, 16);
}

__global__ __launch_bounds__(512, 2) void dcn_fused(
    const unsigned short* __restrict__ xt, const float* __restrict__ off,
    const float* __restrict__ mask, const uint4* __restrict__ wfrag,
    const float* __restrict__ bias, float* __restrict__ out) {
  __shared__ __align__(16) _Float16 Bs[4][4096];  // 32 KB, slot = tile & 3
  __shared__ __align__(16) float swt[9 * 64 * 4];   // 9216 B
  __shared__ __align__(16) int sidx[9 * 64 * 4];    // 9216 B

  const int bid = blockIdx.x;
  const int id = ((bid & 7) << 5) | (bid >> 3);  // XCD-contiguous, bijective
  const int b = id >> 6;
  const int nt = id & 63;  // h row

  const int tid = threadIdx.x;
  const int lane = tid & 63;
  const int wv = tid >> 6;  // 8 waves; wave owns rows wv*32..wv*32+31
  const int lh = lane & 15, lg = lane >> 4;

  // ---- precompute per-(pos,k) tap weights & indices ----
  for (int pair = tid; pair < 576; pair += 512) {
    const int k = pair >> 6;   // 0..8
    const int pl = pair & 63;  // = w
    float oy = off[(((size_t)b * 18 + 2 * k) * 64 + nt) * 64 + pl];
    float ox = off[(((size_t)b * 18 + 2 * k + 1) * 64 + nt) * 64 + pl];
    float m = mask[(((size_t)b * 9 + k) * 64 + nt) * 64 + pl];
    float py = oy + (float)(nt - 1 + k / 3);
    float px = ox + (float)(pl - 1 + k % 3);
    float y0f = floorf(py), x0f = floorf(px);
    float ly = py - y0f, lx = px - x0f;
    float hy = 1.f - ly, hx = 1.f - lx;
    int y0 = (int)y0f, x0 = (int)x0f;
    int y1 = y0 + 1, x1 = x0 + 1;
    bool vy0 = (y0 >= 0) && (y0 < 64);
    bool vy1 = (y1 >= 0) && (y1 < 64);
    bool vx0 = (x0 >= 0) && (x0 < 64);
    bool vx1 = (x1 >= 0) && (x1 < 64);
    int yc0 = min(max(y0, 0), 63), yc1 = min(max(y1, 0), 63);
    int xc0 = min(max(x0, 0), 63), xc1 = min(max(x1, 0), 63);
    int* sp = sidx + (k * 64 + pl) * 4;
    float* wp = swt + (k * 64 + pl) * 4;
    sp[0] = (yc0 * 64 + xc0) * 256;
    sp[1] = (yc0 * 64 + xc1) * 256;
    sp[2] = (yc1 * 64 + xc0) * 256;
    sp[3] = (yc1 * 64 + xc1) * 256;
    wp[0] = (vy0 && vx0) ? hy * hx * m : 0.f;
    wp[1] = (vy0 && vx1) ? hy * lx * m : 0.f;
    wp[2] = (vy1 && vx0) ? ly * hx * m : 0.f;
    wp[3] = (vy1 && vx1) ? ly * lx * m : 0.f;
  }

  // ---- A geometry: coalesced frag-major; wave owns groups wv*2, wv*2+1 ----
  const uint4* aBase = wfrag + (size_t)(wv * 2) * 72 * 64 + lane;

  // ---- B build geometry (verified R12) ----
  const int pos = tid >> 3, ci = tid & 7;
  const unsigned short* xtb = xt + (size_t)b * 1048576 + ci * 8;
  const int bsw = (ci >> 2) * 2048 + pos * 32 + (((ci & 3) ^ ((pos >> 1) & 3)) * 8);

  // ---- MFMA B-fragment offsets ----
  const int csw = (lg ^ ((lh >> 1) & 3)) * 8;
  int boff[4];
#pragma unroll
  for (int fn = 0; fn < 4; ++fn) boff[fn] = (fn * 16 + lh) * 32 + csw;

  // AR4[j]: j&1 = row-group, j>>1 = ksub. Max idx (15*72+71)*64+63 = 73727 OK.
#define LOADA(T, AR4)                                                              \
  do {                                                                             \
    _Pragma("unroll") for (int j = 0; j < 4; ++j)                                  \
        (AR4)[j] = aBase[(size_t)((((j & 1) * 72) + 2 * (T) + (j >> 1)) * 64)];    \
  } while (0)

#define LOADTAPS(T, Q0, Q1, Q2, Q3)                                                \
  do {                                                                             \
    int4 ix = *(const int4*)(sidx + (((T) >> 2) * 64 + pos) * 4);                  \
    const int co = ((T) & 3) * 64;                                                 \
    Q0 = *(const uint4*)(xtb + ix.x + co);                                         \
    Q1 = *(const uint4*)(xtb + ix.y + co);                                         \
    Q2 = *(const uint4*)(xtb + ix.z + co);                                         \
    Q3 = *(const uint4*)(xtb + ix.w + co);                                         \
  } while (0)

#define COMBINE(T, Q0, Q1, Q2, Q3)                                                 \
  do {                                                                             \
    float4 wt4 = *(const float4*)(swt + (((T) >> 2) * 64 + pos) * 4);              \
    combine8(Q0, Q1, Q2, Q3, wt4, &Bs[(T) & 3][0] + bsw);                          \
  } while (0)

#define MFMA_T(T, AR4)                                                             \
  do {                                                                             \
    const _Float16* Bb = &Bs[(T) & 3][0];                                          \
    f16x8 b0[4], b1[4];                                                            \
    _Pragma("unroll") for (int fn = 0; fn < 4; ++fn) {                             \
      b0[fn] = *(const f16x8*)(Bb + boff[fn]);                                     \
      b1[fn] = *(const f16x8*)(Bb + 2048 + boff[fn]);                              \
    }                                                                              \
    __builtin_amdgcn_s_setprio(1);                                                 \
    _Pragma("unroll") for (int fm = 0; fm < 2; ++fm)                               \
        _Pragma("unroll") for (int fn = 0; fn < 4; ++fn) {                         \
      acc[fm][fn] = __builtin_amdgcn_mfma_f32_16x16x32_f16(                        \
          *(const f16x8*)&(AR4)[fm], b0[fn], acc[fm][fn], 0, 0, 0);                \
      acc[fm][fn] = __builtin_amdgcn_mfma_f32_16x16x32_f16(                        \
          *(const f16x8*)&(AR4)[2 + fm], b1[fn], acc[fm][fn], 0, 0, 0);            \
    }                                                                              \
    __builtin_amdgcn_s_setprio(0);                                                 \
  } while (0)

#define BAR()                                                                      \
  do {                                                                             \
    asm volatile("s_waitcnt lgkmcnt(0)" ::: "memory");                             \
    __builtin_amdgcn_sched_barrier(0);                                             \
    __builtin_amdgcn_s_barrier();                                                  \
    __builtin_amdgcn_sched_barrier(0);                                             \
  } while (0)

  // superphase S (tiles T0=2S, T0+1): MFMA both from ACUR; load A(T0+2,T0+3)
  // into ANXT; combine(T0+2) from qA then reload qA with taps(T0+4); same for
  // qB/T0+3/T0+5; one lgkm-only barrier. Slots: reads (2S)&3,(2S+1)&3; writes
  // (2S+2)&3,(2S+3)&3 — disjoint; WAR separated by the barrier.
#define SUPER(S_, ACUR, ANXT)                                                      \
  do {                                                                             \
    MFMA_T(2 * (S_), ACUR);                                                        \
    MFMA_T(2 * (S_) + 1, (ACUR) + 4);                                              \
    LOADA(2 * (S_) + 2, ANXT);                                                     \
    LOADA(2 * (S_) + 3, (ANXT) + 4);                                               \
    COMBINE(2 * (S_) + 2, qA0, qA1, qA2, qA3);                                     \
    LOADTAPS(2 * (S_) + 4, qA0, qA1, qA2, qA3);                                    \
    COMBINE(2 * (S_) + 3, qB0, qB1, qB2, qB3);                                     \
    LOADTAPS(2 * (S_) + 5, qB0, qB1, qB2, qB3);                                    \
    BAR();                                                                         \
  } while (0)

  f32x4 acc[2][4] = {};
  uint4 AE[8], AO[8];
  uint4 qA0, qA1, qA2, qA3, qB0, qB1, qB2, qB3;

  __syncthreads();  // swt/sidx ready

  // ---- prologue: combine tiles 0,1 -> slots 0,1; A(0,1)->AE; taps(2,3) ----
  {
    LOADTAPS(0, qA0, qA1, qA2, qA3);
    LOADTAPS(1, qB0, qB1, qB2, qB3);
    COMBINE(0, qA0, qA1, qA2, qA3);
    COMBINE(1, qB0, qB1, qB2, qB3);
    LOADA(0, AE);
    LOADA(1, AE + 4);
    LOADTAPS(2, qA0, qA1, qA2, qA3);
    LOADTAPS(3, qB0, qB1, qB2, qB3);
    BAR();
  }

  for (int s = 0; s < 16; s += 2) {
    SUPER(s, AE, AO);
    SUPER(s + 1, AO, AE);
  }
  // ---- S=16: MFMA 32,33 (AE); load A(34,35)->AO; combine 34,35; no taps ----
  {
    MFMA_T(32, AE);
    MFMA_T(33, AE + 4);
    LOADA(34, AO);
    LOADA(35, AO + 4);
    COMBINE(34, qA0, qA1, qA2, qA3);
    COMBINE(35, qB0, qB1, qB2, qB3);
    BAR();
  }
  // ---- S=17: MFMA 34,35 ----
  MFMA_T(34, AO);
  MFMA_T(35, AO + 4);

  // ---- epilogue ----
  float* outb = out + (size_t)b * 1048576 + (size_t)nt * 64;
#pragma unroll
  for (int fm = 0; fm < 2; ++fm) {
#pragma unroll
    for (int i = 0; i < 4; ++i) {
      const int o = wv * 32 + fm * 16 + lg * 4 + i;
      const float bs = bias[o];
      float* orow = outb + (size_t)o * 4096 + lh;
#pragma unroll
      for (int fn = 0; fn < 4; ++fn) orow[fn * 16] = acc[fm][fn][i] + bs;
    }
  }
#undef LOADA
#undef LOADTAPS
#undef COMBINE
#undef MFMA_T
#undef BAR
#undef SUPER
}

extern "C" void kernel_launch(void* const* d_in, const int* in_sizes, int n_in,
                              void* d_out, int out_size, void* d_ws, size_t ws_size,
                              hipStream_t stream) {
  const float* x = (const float*)d_in[0];
  const float* off = (const float*)d_in[1];
  const float* mask = (const float*)d_in[2];
  const float* wgt = (const float*)d_in[3];
  const float* bias = (const float*)d_in[4];
  float* out = (float*)d_out;

  uint4* wfrag = (uint4*)d_ws;                              // 73728*16B = 1.18 MB
  unsigned short* xtp = (unsigned short*)(wfrag + 73728);   // 8.4 MB

  prep_wx<<<1312, 256, 0, stream>>>(x, wgt, xtp, wfrag);
  dcn_fused<<<256, 512, 0, stream>>>(xtp, off, mask, wfrag, bias, out);
}